// Round 12
// baseline (104.584 us; speedup 1.0000x reference)
//
#include <hip/hip_runtime.h>
#include <hip/hip_fp16.h>

#define PP 9216   // 96*96 pixels per batch

typedef _Float16 f16x8 __attribute__((ext_vector_type(8)));
typedef _Float16 f16x4 __attribute__((ext_vector_type(4)));
typedef float    f32x4 __attribute__((ext_vector_type(4)));

// swizzled half-index within a 128-half (256B, 16x16B-chunk) row
__device__ __forceinline__ int swz128(int row, int hc) {
    return row * 128 + (((hc >> 3) ^ (row & 15)) << 3) + (hc & 7);
}
// swizzled half-index within a 64-half (128B, 8x16B-chunk) row
__device__ __forceinline__ int swz64(int row, int hc) {
    return row * 64 + (((hc >> 3) ^ (row & 7)) << 3) + (hc & 7);
}
// swizzled half-index within a 32-half (64B, 4x16B-chunk) row
__device__ __forceinline__ int swz32(int row, int hc) {
    return row * 32 + ((((hc >> 3) ^ (row & 3)) & 3) << 3) + (hc & 7);
}

__device__ __forceinline__ f16x8 zero8() {
    f16x8 z;
    #pragma unroll
    for (int e = 0; e < 8; e++) z[e] = (_Float16)0;
    return z;
}

// ---------------------------------------------------------------------------
// prep_w: one-time f32 -> f16 weight conversion.
// wqkv16[o][c], o in [0,384): 0-127 wq, 128-255 wk, 256-383 wv. wp16[c][o].
// ---------------------------------------------------------------------------
__global__ __launch_bounds__(256) void prep_w(
    const float* __restrict__ wq, const float* __restrict__ wk,
    const float* __restrict__ wv, const float* __restrict__ wp,
    _Float16* __restrict__ wqkv16, _Float16* __restrict__ wp16)
{
    int e = (blockIdx.x * 256 + threadIdx.x) * 4;   // 4 elems/thread, 65536 total
    const float* src;
    _Float16* dst;
    if (e < 49152) {
        int o = e >> 7;
        src = (o < 128) ? (wq + (size_t)o * 128)
            : (o < 256) ? (wk + (size_t)(o - 128) * 128)
                        : (wv + (size_t)(o - 256) * 128);
        src += (e & 127);
        dst = wqkv16 + e;
    } else {
        int j = e - 49152;
        src = wp + j;
        dst = wp16 + j;
    }
    float4 v = *(const float4*)src;
    f16x4 h;
    h[0] = (_Float16)v.x; h[1] = (_Float16)v.y;
    h[2] = (_Float16)v.z; h[3] = (_Float16)v.w;
    *(f16x4*)dst = h;
}

// ---------------------------------------------------------------------------
// QKV GEMM: qkv[b][p][o] = sum_c x[b][c][p] * wqkv[o][c], f16 out.
// Block 64px x 192o (grid 144,2,2), wave 32px x 96o. x staged through LDS
// with in-block transpose+cvt (float2-vectorized coalesced f32 reads);
// LDS epilogue for coalesced 16B stores. One barrier.
// ---------------------------------------------------------------------------
__global__ __launch_bounds__(256) void qkv_gemm(
    const float* __restrict__ x, const _Float16* __restrict__ wqkv,
    _Float16* __restrict__ qkvout)
{
    __shared__ __align__(16) char smem[43008];
    _Float16* sX   = (_Float16*)smem;               // [64 px][128 c] swz128, 16KB
    _Float16* sEpi = (_Float16*)(smem + 16384);     // 4 wave strips [32][104]

    const int t = threadIdx.x;
    const int w = t >> 6, lane = t & 63, lm = lane & 15, quad = lane >> 4;
    const int b = blockIdx.z;
    const int p0 = blockIdx.x * 64;
    const int nbase = blockIdx.y * 192;

    const float* xb = x + (size_t)b * 128 * PP;
    _Float16* qout = qkvout + (size_t)b * PP * 384;

    // stage x tile: float2 (2 px) x 16 channels per thread, coalesced reads
    {
        const int px2 = (t & 31) * 2;
        const int cb = t >> 5;              // 0..7
        #pragma unroll
        for (int i = 0; i < 16; i++) {
            int c = cb + i * 8;
            float2 v = *(const float2*)(xb + (size_t)c * PP + p0 + px2);
            sX[swz128(px2,     c)] = (_Float16)v.x;
            sX[swz128(px2 + 1, c)] = (_Float16)v.y;
        }
    }
    __syncthreads();

    const int ms0 = (w & 1) * 32;
    const int nw = (w >> 1) * 96;

    f16x8 A[2][4];
    #pragma unroll
    for (int ms = 0; ms < 2; ms++)
        #pragma unroll
        for (int kc = 0; kc < 4; kc++)
            A[ms][kc] = *(const f16x8*)(sX + swz128(ms0 + ms * 16 + lm, kc * 32 + quad * 8));

    _Float16* strip = sEpi + w * 3328;   // [32 rows][104]
    #pragma unroll
    for (int nt = 0; nt < 6; nt++) {
        const int o = nbase + nw + nt * 16 + lm;
        const _Float16* wr = wqkv + (size_t)o * 128;
        f16x8 Bf[4];
        #pragma unroll
        for (int kc = 0; kc < 4; kc++)
            Bf[kc] = *(const f16x8*)(wr + kc * 32 + quad * 8);
        #pragma unroll
        for (int ms = 0; ms < 2; ms++) {
            f32x4 acc = {0.f, 0.f, 0.f, 0.f};
            #pragma unroll
            for (int kc = 0; kc < 4; kc++)
                acc = __builtin_amdgcn_mfma_f32_16x16x32_f16(A[ms][kc], Bf[kc], acc, 0, 0, 0);
            #pragma unroll
            for (int r = 0; r < 4; r++)
                strip[(ms * 16 + quad * 4 + r) * 104 + nt * 16 + lm] = (_Float16)acc[r];
        }
    }

    // wave-local epilogue: 32 rows x 96 halfs -> coalesced 16B stores
    #pragma unroll
    for (int it = 0; it < 6; it++) {
        int idx = it * 64 + lane;      // 0..383
        int row = idx / 12;            // 0..31
        int ch  = idx % 12;            // 16B chunk within row
        uint4 v = *(const uint4*)&strip[row * 104 + ch * 8];
        *(uint4*)(qout + (size_t)(p0 + ms0 + row) * 384 + nbase + nw + ch * 8) = v;
    }
}

// ---------------------------------------------------------------------------
// Fused attention+proj, TWO adjacent 4x4 tiles per 512-thread block.
// Waves 0-3 = tile A (sub=0), waves 4-7 = tile B (sub=1); disjoint 24KB LDS
// halves; ONE shared barrier. Packs 8 waves into each HW block-slot (the
// R5-R10 rounds showed blocks/CU pins near 4 regardless of LDS/VGPR, so TLP
// is raised per-slot instead). Per-tile: wave w = head w; Q/K gathered from
// global (L2-hot); V transposed into wave slab; register softmax; sAo
// overlays dead sP (same-wave in-order LDS). launch_bounds(512,2): VGPR cap
// ~128 >> need (~64), no spill; LDS 48KB -> 3 blocks/CU = 24 waves.
// ---------------------------------------------------------------------------
__global__ __launch_bounds__(512, 2) void attn_fused(
    const _Float16* __restrict__ qkv, const _Float16* __restrict__ wp16,
    float* __restrict__ out)
{
    __shared__ __align__(16) char smem[49152];
    const int t = threadIdx.x;
    const int sub = t >> 8;                 // which tile of the pair
    const int tl = t & 255;
    const int w = tl >> 6, lane = tl & 63, lm = lane & 15, quad = lane >> 4;

    // XCD-bijective swizzle over 576 blocks = 8 XCDs x 72; the pair covers
    // jobs {2*wg, 2*wg+1} = adjacent x-tiles (shared halo columns -> L2).
    const int wg = (blockIdx.x & 7) * 72 + (blockIdx.x >> 3);
    const int j = wg * 2 + sub;             // 0..1151
    const int b = j / 576;
    const int rem = j - b * 576;
    const int x0 = (rem % 24) * 4, y0 = (rem / 24) * 4;

    const _Float16* qb = qkv + (size_t)b * PP * 384;
    float* ob = out + (size_t)b * 128 * PP;

    char* base = smem + sub * 24576;
    _Float16* sVT = (_Float16*)(base + w * 6144);          // [32 d][64 pos] swz64
    _Float16* sPh = (_Float16*)(base + w * 6144 + 4096);   // [16 px][64 pos] swz64
    _Float16* sAoW= (_Float16*)(base + w * 6144 + 4096);   // overlay: [16][32] swz32

    // ---- stage V^T for head w: lane = pos; gather 64B, write transposed.
    {
        const int pos = lane;
        const int gy = y0 - 2 + (pos >> 3), gx = x0 - 2 + (pos & 7);
        const bool valid = ((unsigned)gy < 96u) && ((unsigned)gx < 96u);
        const int gp = valid ? (gy * 96 + gx) : 0;
        const _Float16* vsrc = qb + (size_t)gp * 384 + 256 + w * 32;
        f16x8 vv[4];
        #pragma unroll
        for (int jj = 0; jj < 4; jj++) {
            f16x8 ld = *(const f16x8*)(vsrc + jj * 8);
            vv[jj] = valid ? ld : zero8();
        }
        #pragma unroll
        for (int jj = 0; jj < 4; jj++)
            #pragma unroll
            for (int e = 0; e < 8; e++) {
                int d = jj * 8 + e;
                sVT[d * 64 + ((((pos >> 3)) ^ (d & 7)) << 3) + (pos & 7)] = vv[jj][e];
            }
    }

    // ---- Q A-frag: lane (lm,quad) holds Q[px=lm][d=quad*8..+8]
    const int gpq = (y0 + (lm >> 2)) * 96 + x0 + (lm & 3);
    f16x8 Aq = *(const f16x8*)(qb + (size_t)gpq * 384 + w * 32 + quad * 8);

    // ---- QK^T: K B-frags gathered directly from global; OOB pos -> 0 rows
    f32x4 S[4];
    #pragma unroll
    for (int n = 0; n < 4; n++) {
        int pos = n * 16 + lm;
        int gy = y0 - 2 + (pos >> 3), gx = x0 - 2 + (pos & 7);
        bool valid = ((unsigned)gy < 96u) && ((unsigned)gx < 96u);
        int gp = valid ? (gy * 96 + gx) : 0;
        f16x8 ld = *(const f16x8*)(qb + (size_t)gp * 384 + 128 + w * 32 + quad * 8);
        f16x8 Bk = valid ? ld : zero8();
        f32x4 z = {0.f, 0.f, 0.f, 0.f};
        S[n] = __builtin_amdgcn_mfma_f32_16x16x32_f16(Aq, Bk, z, 0, 0, 0);
    }

    // ---- softmax on fragments. px=(quad,r): window hy in [quad,quad+5),
    // hx in [r,r+5). Reduce in-lane over n + shfl over the 16-lane group.
    float inv4[4];
    {
        const float scale = 0.17677669529663689f;
        #pragma unroll
        for (int r = 0; r < 4; r++) {
            float e[4];
            float mx = -1e30f;
            #pragma unroll
            for (int n = 0; n < 4; n++) {
                int hy = n * 2 + (lm >> 3), hx = lm & 7;
                bool memb = (hy >= quad) && (hy < quad + 5) && (hx >= r) && (hx < r + 5);
                e[n] = memb ? S[n][r] * scale : -1e30f;
                mx = fmaxf(mx, e[n]);
            }
            mx = fmaxf(mx, __shfl_xor(mx, 1));
            mx = fmaxf(mx, __shfl_xor(mx, 2));
            mx = fmaxf(mx, __shfl_xor(mx, 4));
            mx = fmaxf(mx, __shfl_xor(mx, 8));
            float sum = 0.f;
            #pragma unroll
            for (int n = 0; n < 4; n++) {
                float ev = __expf(e[n] - mx);   // masked -> exp(-huge) == 0
                e[n] = ev;
                sum += ev;
            }
            sum += __shfl_xor(sum, 1);
            sum += __shfl_xor(sum, 2);
            sum += __shfl_xor(sum, 4);
            sum += __shfl_xor(sum, 8);
            inv4[r] = 1.f / sum;
            #pragma unroll
            for (int n = 0; n < 4; n++)
                sPh[swz64(quad * 4 + r, n * 16 + lm)] = (_Float16)e[n];
        }
    }

    // ---- PV: out[px][d] = (sum_pos P*V) * inv. All sP reads are issued
    // before the sAo overlay writes (same-wave in-order LDS -> safe).
    {
        f32x4 acc2[2] = {{0.f, 0.f, 0.f, 0.f}, {0.f, 0.f, 0.f, 0.f}};
        #pragma unroll
        for (int kc = 0; kc < 2; kc++) {
            f16x8 Ap = *(const f16x8*)(sPh + swz64(lm, kc * 32 + quad * 8));
            #pragma unroll
            for (int nd = 0; nd < 2; nd++) {
                int row = nd * 16 + lm;          // d
                int hc = kc * 32 + quad * 8;     // pos chunk
                f16x8 Bv = *(const f16x8*)(sVT + row * 64
                               + (((hc >> 3) ^ (row & 7)) << 3) + (hc & 7));
                acc2[nd] = __builtin_amdgcn_mfma_f32_16x16x32_f16(Ap, Bv, acc2[nd], 0, 0, 0);
            }
        }
        #pragma unroll
        for (int nd = 0; nd < 2; nd++)
            #pragma unroll
            for (int r = 0; r < 4; r++)
                sAoW[swz32(quad * 4 + r, nd * 16 + lm)] =
                    (_Float16)(acc2[nd][r] * inv4[r]);
    }
    __syncthreads();                      // the ONE barrier: all sAo complete

    // ---- proj: out[c][px] = sum_o wp[c][o] * ao[px][o].
    // o-chunk kc*32+quad*8 lives entirely in wave-slab kc of the same tile.
    {
        f16x8 Bf[4];
        #pragma unroll
        for (int kc = 0; kc < 4; kc++) {
            const _Float16* slab = (const _Float16*)(base + kc * 6144 + 4096);
            Bf[kc] = *(const f16x8*)(slab + swz32(lm, quad * 8));
        }
        int gp = (y0 + (lm >> 2)) * 96 + x0 + (lm & 3);
        #pragma unroll
        for (int mi = 0; mi < 2; mi++) {
            const _Float16* wr = wp16 + (size_t)((w * 2 + mi) * 16 + lm) * 128;
            f32x4 acc = {0.f, 0.f, 0.f, 0.f};
            #pragma unroll
            for (int kc = 0; kc < 4; kc++)
                acc = __builtin_amdgcn_mfma_f32_16x16x32_f16(
                    *(const f16x8*)(wr + kc * 32 + quad * 8), Bf[kc], acc, 0, 0, 0);
            int c0 = (w * 2 + mi) * 16 + quad * 4;
            #pragma unroll
            for (int r = 0; r < 4; r++)
                ob[(size_t)(c0 + r) * PP + gp] = acc[r];
        }
    }
}

extern "C" void kernel_launch(void* const* d_in, const int* in_sizes, int n_in,
                              void* d_out, int out_size, void* d_ws, size_t ws_size,
                              hipStream_t stream)
{
    const float* x  = (const float*)d_in[0];
    const float* wq = (const float*)d_in[1];
    const float* wk = (const float*)d_in[2];
    const float* wv = (const float*)d_in[3];
    const float* wp = (const float*)d_in[4];
    float* out = (float*)d_out;

    _Float16* wqkv16 = (_Float16*)d_ws;          // 384*128
    _Float16* wp16   = wqkv16 + 49152;           // 128*128
    _Float16* qkvh   = wp16 + 16384;             // 2*9216*384

    prep_w<<<dim3(64), 256, 0, stream>>>(wq, wk, wv, wp, wqkv16, wp16);
    qkv_gemm<<<dim3(144, 2, 2), 256, 0, stream>>>(x, wqkv16, qkvh);
    attn_fused<<<dim3(576), 512, 0, stream>>>(qkvh, wp16, out);
}

// Round 13
// 102.295 us; speedup vs baseline: 1.0224x; 1.0224x over previous
//
#include <hip/hip_runtime.h>
#include <hip/hip_fp16.h>

#define PP 9216   // 96*96 pixels per batch

typedef _Float16 f16x8 __attribute__((ext_vector_type(8)));
typedef _Float16 f16x4 __attribute__((ext_vector_type(4)));
typedef float    f32x4 __attribute__((ext_vector_type(4)));

// swizzled half-index within a 128-half (256B, 16x16B-chunk) row
__device__ __forceinline__ int swz128(int row, int hc) {
    return row * 128 + (((hc >> 3) ^ (row & 15)) << 3) + (hc & 7);
}
// swizzled half-index within a 64-half (128B, 8x16B-chunk) row
__device__ __forceinline__ int swz64(int row, int hc) {
    return row * 64 + (((hc >> 3) ^ (row & 7)) << 3) + (hc & 7);
}

__device__ __forceinline__ f16x8 zero8() {
    f16x8 z;
    #pragma unroll
    for (int e = 0; e < 8; e++) z[e] = (_Float16)0;
    return z;
}

// ---------------------------------------------------------------------------
// prep_w: one-time f32 -> f16 weight conversion.
// wqkv16[o][c], o in [0,384): 0-127 wq, 128-255 wk, 256-383 wv. wp16[c][o].
// ---------------------------------------------------------------------------
__global__ __launch_bounds__(256) void prep_w(
    const float* __restrict__ wq, const float* __restrict__ wk,
    const float* __restrict__ wv, const float* __restrict__ wp,
    _Float16* __restrict__ wqkv16, _Float16* __restrict__ wp16)
{
    int e = (blockIdx.x * 256 + threadIdx.x) * 4;   // 4 elems/thread, 65536 total
    const float* src;
    _Float16* dst;
    if (e < 49152) {
        int o = e >> 7;
        src = (o < 128) ? (wq + (size_t)o * 128)
            : (o < 256) ? (wk + (size_t)(o - 128) * 128)
                        : (wv + (size_t)(o - 256) * 128);
        src += (e & 127);
        dst = wqkv16 + e;
    } else {
        int j = e - 49152;
        src = wp + j;
        dst = wp16 + j;
    }
    float4 v = *(const float4*)src;
    f16x4 h;
    h[0] = (_Float16)v.x; h[1] = (_Float16)v.y;
    h[2] = (_Float16)v.z; h[3] = (_Float16)v.w;
    *(f16x4*)dst = h;
}

// ---------------------------------------------------------------------------
// QKV GEMM: qkv[b][p][o] = sum_c x[b][c][p] * wqkv[o][c], f16 out.
// Block 64px x 192o (grid 144,2,2), wave 32px x 96o. x staged through LDS
// with in-block transpose+cvt (float2-vectorized coalesced f32 reads);
// LDS epilogue for coalesced 16B stores. One barrier.
// ---------------------------------------------------------------------------
__global__ __launch_bounds__(256) void qkv_gemm(
    const float* __restrict__ x, const _Float16* __restrict__ wqkv,
    _Float16* __restrict__ qkvout)
{
    __shared__ __align__(16) char smem[43008];
    _Float16* sX   = (_Float16*)smem;               // [64 px][128 c] swz128, 16KB
    _Float16* sEpi = (_Float16*)(smem + 16384);     // 4 wave strips [32][104]

    const int t = threadIdx.x;
    const int w = t >> 6, lane = t & 63, lm = lane & 15, quad = lane >> 4;
    const int b = blockIdx.z;
    const int p0 = blockIdx.x * 64;
    const int nbase = blockIdx.y * 192;

    const float* xb = x + (size_t)b * 128 * PP;
    _Float16* qout = qkvout + (size_t)b * PP * 384;

    // stage x tile: float2 (2 px) x 16 channels per thread, coalesced reads
    {
        const int px2 = (t & 31) * 2;
        const int cb = t >> 5;              // 0..7
        #pragma unroll
        for (int i = 0; i < 16; i++) {
            int c = cb + i * 8;
            float2 v = *(const float2*)(xb + (size_t)c * PP + p0 + px2);
            sX[swz128(px2,     c)] = (_Float16)v.x;
            sX[swz128(px2 + 1, c)] = (_Float16)v.y;
        }
    }
    __syncthreads();

    const int ms0 = (w & 1) * 32;
    const int nw = (w >> 1) * 96;

    f16x8 A[2][4];
    #pragma unroll
    for (int ms = 0; ms < 2; ms++)
        #pragma unroll
        for (int kc = 0; kc < 4; kc++)
            A[ms][kc] = *(const f16x8*)(sX + swz128(ms0 + ms * 16 + lm, kc * 32 + quad * 8));

    _Float16* strip = sEpi + w * 3328;   // [32 rows][104]
    #pragma unroll
    for (int nt = 0; nt < 6; nt++) {
        const int o = nbase + nw + nt * 16 + lm;
        const _Float16* wr = wqkv + (size_t)o * 128;
        f16x8 Bf[4];
        #pragma unroll
        for (int kc = 0; kc < 4; kc++)
            Bf[kc] = *(const f16x8*)(wr + kc * 32 + quad * 8);
        #pragma unroll
        for (int ms = 0; ms < 2; ms++) {
            f32x4 acc = {0.f, 0.f, 0.f, 0.f};
            #pragma unroll
            for (int kc = 0; kc < 4; kc++)
                acc = __builtin_amdgcn_mfma_f32_16x16x32_f16(A[ms][kc], Bf[kc], acc, 0, 0, 0);
            #pragma unroll
            for (int r = 0; r < 4; r++)
                strip[(ms * 16 + quad * 4 + r) * 104 + nt * 16 + lm] = (_Float16)acc[r];
        }
    }

    // wave-local epilogue: 32 rows x 96 halfs -> coalesced 16B stores
    #pragma unroll
    for (int it = 0; it < 6; it++) {
        int idx = it * 64 + lane;      // 0..383
        int row = idx / 12;            // 0..31
        int ch  = idx % 12;            // 16B chunk within row
        uint4 v = *(const uint4*)&strip[row * 104 + ch * 8];
        *(uint4*)(qout + (size_t)(p0 + ms0 + row) * 384 + nbase + nw + ch * 8) = v;
    }
}

// ---------------------------------------------------------------------------
// Fused attention+proj, one block per (4x4 tile, batch); wave w = head w.
// SWAPPED-OPERAND structure:
//   S^T = mfma(K, Q): px lands on the lane axis (px=lm) -> softmax needs
//     only 4 shfls (xor 16/32) and one scalar inv per lane.
//   PV  = mfma(V^T, P): V^T is the A-fragment, gathered DIRECTLY from global
//     as 32 scalar loads (8 positions/frag share one halo row; 16 lanes read
//     32B contiguous) -> no V LDS transpose at all.
// P relayout through a 2KB/wave LDS slab (16 scalar writes + 2 b128 reads).
// LDS 12KB; ONE barrier (before proj). launch_bounds(256,4) = proven 64-VGPR
// no-spill operating point.
// ---------------------------------------------------------------------------
__global__ __launch_bounds__(256, 4) void attn_fused(
    const _Float16* __restrict__ qkv, const _Float16* __restrict__ wp16,
    float* __restrict__ out)
{
    __shared__ __align__(16) char smem[12288];
    const int t = threadIdx.x;
    const int w = t >> 6, lane = t & 63, lm = lane & 15, quad = lane >> 4;

    // XCD-bijective swizzle: 1152 = 8 XCDs x 144 contiguous blocks
    const int wgid = (blockIdx.x & 7) * 144 + (blockIdx.x >> 3);
    const int b = wgid / 576;
    const int rem = wgid - b * 576;
    const int x0 = (rem % 24) * 4, y0 = (rem / 24) * 4;

    const _Float16* qb = qkv + (size_t)b * PP * 384;
    float* ob = out + (size_t)b * 128 * PP;

    _Float16* sPh = (_Float16*)(smem + w * 2048);    // [16 px][64 pos] swz64
    _Float16* sAo = (_Float16*)(smem + 8192);        // [16 px][128 o] swz128

    // ---- Q B-frag: B[n=px=lm][k=d=quad*8+j]
    const int gpq = (y0 + (lm >> 2)) * 96 + x0 + (lm & 3);
    f16x8 Bq = *(const f16x8*)(qb + (size_t)gpq * 384 + w * 32 + quad * 8);

    // ---- S^T = mfma(K, Q): A-frag tile n = K[pos=n*16+lm][d chunk].
    // Lane ends holding S[pos=n*16+quad*4+r][px=lm].
    f32x4 S[4];
    #pragma unroll
    for (int n = 0; n < 4; n++) {
        int pos = n * 16 + lm;
        int gy = y0 - 2 + (pos >> 3), gx = x0 - 2 + (pos & 7);
        bool valid = ((unsigned)gy < 96u) && ((unsigned)gx < 96u);
        int gp = valid ? (gy * 96 + gx) : 0;
        f16x8 ld = *(const f16x8*)(qb + (size_t)gp * 384 + 128 + w * 32 + quad * 8);
        f16x8 Ak = valid ? ld : zero8();
        f32x4 z = {0.f, 0.f, 0.f, 0.f};
        S[n] = __builtin_amdgcn_mfma_f32_16x16x32_f16(Ak, Bq, z, 0, 0, 0);
    }

    // ---- softmax over pos for px=lm: 16 in-lane values + xor16/32 shfls.
    // Window for px=(py,pxx)=(lm>>2, lm&3): hy in [py,py+5), hx in [pxx,pxx+5).
    float ev[4][4];
    float inv;
    {
        const float scale = 0.17677669529663689f;
        const int py = lm >> 2, pxx = lm & 3;
        float mx = -1e30f;
        #pragma unroll
        for (int n = 0; n < 4; n++)
            #pragma unroll
            for (int r = 0; r < 4; r++) {
                int pos = n * 16 + quad * 4 + r;
                int hy = pos >> 3, hx = pos & 7;
                bool memb = (hy >= py) && (hy < py + 5) && (hx >= pxx) && (hx < pxx + 5);
                float sj = memb ? S[n][r] * scale : -1e30f;
                ev[n][r] = sj;
                mx = fmaxf(mx, sj);
            }
        mx = fmaxf(mx, __shfl_xor(mx, 16));
        mx = fmaxf(mx, __shfl_xor(mx, 32));
        float sum = 0.f;
        #pragma unroll
        for (int n = 0; n < 4; n++)
            #pragma unroll
            for (int r = 0; r < 4; r++) {
                float e = __expf(ev[n][r] - mx);   // masked -> exp(-huge) == 0
                ev[n][r] = e;
                sum += e;
            }
        sum += __shfl_xor(sum, 16);
        sum += __shfl_xor(sum, 32);
        inv = 1.f / sum;
    }

    // ---- P relayout via wave-local LDS slab (same-wave in-order: safe)
    #pragma unroll
    for (int n = 0; n < 4; n++)
        #pragma unroll
        for (int r = 0; r < 4; r++)
            sPh[swz64(lm, n * 16 + quad * 4 + r)] = (_Float16)ev[n][r];

    // ---- V^T A-frags gathered directly from global.
    // Frag (nd,kc): V[pos=kc*32+quad*8+j][d=nd*16+lm]; gy fixed per (kc,quad).
    f16x8 Av[2][2];
    #pragma unroll
    for (int kc = 0; kc < 2; kc++) {
        const int gy = y0 - 2 + kc * 4 + quad;
        const bool vy = (unsigned)gy < 96u;
        #pragma unroll
        for (int nd = 0; nd < 2; nd++) {
            const int ch = 256 + w * 32 + nd * 16 + lm;
            #pragma unroll
            for (int j = 0; j < 8; j++) {
                int gx = x0 - 2 + j;
                bool valid = vy && ((unsigned)gx < 96u);
                _Float16 v = (_Float16)0;
                if (valid) v = qb[(size_t)(gy * 96 + gx) * 384 + ch];
                Av[nd][kc][j] = v;
            }
        }
    }

    // ---- PV: out^T[d][px] = mfma(V^T, P); multiply by inv (per-lane px=lm)
    {
        f32x4 acc[2] = {{0.f, 0.f, 0.f, 0.f}, {0.f, 0.f, 0.f, 0.f}};
        #pragma unroll
        for (int kc = 0; kc < 2; kc++) {
            f16x8 Bp = *(const f16x8*)(sPh + swz64(lm, kc * 32 + quad * 8));
            #pragma unroll
            for (int nd = 0; nd < 2; nd++)
                acc[nd] = __builtin_amdgcn_mfma_f32_16x16x32_f16(
                    Av[nd][kc], Bp, acc[nd], 0, 0, 0);
        }
        // D[row=d_local=quad*4+r][col=px=lm], d = nd*16+quad*4+r
        #pragma unroll
        for (int nd = 0; nd < 2; nd++)
            #pragma unroll
            for (int r = 0; r < 4; r++)
                sAo[swz128(lm, w * 32 + nd * 16 + quad * 4 + r)] =
                    (_Float16)(acc[nd][r] * inv);
    }
    __syncthreads();                      // the ONE barrier: sAo complete

    // ---- proj: out[c][px] = sum_o wp[c][o] * ao[px][o]
    {
        f16x8 Bf[4];
        #pragma unroll
        for (int kc = 0; kc < 4; kc++)
            Bf[kc] = *(const f16x8*)(sAo + swz128(lm, kc * 32 + quad * 8));
        int gp = (y0 + (lm >> 2)) * 96 + x0 + (lm & 3);
        #pragma unroll
        for (int mi = 0; mi < 2; mi++) {
            const _Float16* wr = wp16 + (size_t)((w * 2 + mi) * 16 + lm) * 128;
            f32x4 acc = {0.f, 0.f, 0.f, 0.f};
            #pragma unroll
            for (int kc = 0; kc < 4; kc++)
                acc = __builtin_amdgcn_mfma_f32_16x16x32_f16(
                    *(const f16x8*)(wr + kc * 32 + quad * 8), Bf[kc], acc, 0, 0, 0);
            int c0 = (w * 2 + mi) * 16 + quad * 4;
            #pragma unroll
            for (int r = 0; r < 4; r++)
                ob[(size_t)(c0 + r) * PP + gp] = acc[r];
        }
    }
}

extern "C" void kernel_launch(void* const* d_in, const int* in_sizes, int n_in,
                              void* d_out, int out_size, void* d_ws, size_t ws_size,
                              hipStream_t stream)
{
    const float* x  = (const float*)d_in[0];
    const float* wq = (const float*)d_in[1];
    const float* wk = (const float*)d_in[2];
    const float* wv = (const float*)d_in[3];
    const float* wp = (const float*)d_in[4];
    float* out = (float*)d_out;

    _Float16* wqkv16 = (_Float16*)d_ws;          // 384*128
    _Float16* wp16   = wqkv16 + 49152;           // 128*128
    _Float16* qkvh   = wp16 + 16384;             // 2*9216*384

    prep_w<<<dim3(64), 256, 0, stream>>>(wq, wk, wv, wp, wqkv16, wp16);
    qkv_gemm<<<dim3(144, 2, 2), 256, 0, stream>>>(x, wqkv16, qkvh);
    attn_fused<<<dim3(1152), 256, 0, stream>>>(qkvh, wp16, out);
}